// Round 1
// baseline (560.008 us; speedup 1.0000x reference)
//
#include <hip/hip_runtime.h>

// WindowAttention3D: B=1024, N1=256, N2=128, C=128, NH=4, hd=32, nW=64
// out = [x (1024*256*128 f32)] ++ [attn (1024*4*256*128 f32)]

typedef __attribute__((ext_vector_type(8))) short s16x8;
typedef __attribute__((ext_vector_type(4))) short s16x4;
typedef __attribute__((ext_vector_type(4))) float f32x4;

static __device__ __forceinline__ unsigned short f2bf(float f) {
  union { float f; unsigned u; } v; v.f = f;
  unsigned r = v.u + 0x7FFFu + ((v.u >> 16) & 1u);
  return (unsigned short)(r >> 16);
}

// ---------------- prep: weights->bf16, rpb bias gather ----------------
__global__ void kw_prep(const float* __restrict__ qw, const float* __restrict__ kvw,
                        const float* __restrict__ pw, const float* __restrict__ rpb,
                        const int* __restrict__ relidx,
                        unsigned short* __restrict__ qwb, unsigned short* __restrict__ kvwb,
                        unsigned short* __restrict__ pwb, float* __restrict__ bias) {
  int tid = blockIdx.x * 256 + threadIdx.x;
  int stride = gridDim.x * 256;
  for (int i = tid; i < 65536; i += stride) {
    if (i < 16384)      qwb[i] = f2bf(qw[i]);
    else if (i < 49152) kvwb[i - 16384] = f2bf(kvw[i - 16384]);
    else                pwb[i - 49152] = f2bf(pw[i - 49152]);
  }
  // bias[h][q][n2] = rpb[rel_index[q][n2]][h]
  for (int i = tid; i < 32768; i += stride) {
    int rel = relidx[i];
    float4 t = *(const float4*)(rpb + rel * 4);
    bias[i]          = t.x;
    bias[32768 + i]  = t.y;
    bias[65536 + i]  = t.z;
    bias[98304 + i]  = t.w;
  }
}

// ---------------- q projection: qh = (q @ qw^T + qb) * scale, bf16 ----------------
__global__ __launch_bounds__(256) void kq(const float* __restrict__ q,
    const unsigned short* __restrict__ qwb, const float* __restrict__ qb,
    unsigned short* __restrict__ qh) {
  __shared__ unsigned short qL[64][136];
  int b = blockIdx.x >> 2, q0 = (blockIdx.x & 3) << 6;
  int t = threadIdx.x;
  const float4* src = (const float4*)(q + (b * 256 + q0) * 128);
#pragma unroll
  for (int i = 0; i < 8; ++i) {
    int idx = t + i * 256;                 // 2048 float4 = 64 rows x 128 f32
    float4 v = src[idx];
    unsigned short* d = &qL[idx >> 5][(idx & 31) * 4];
    d[0] = f2bf(v.x); d[1] = f2bf(v.y); d[2] = f2bf(v.z); d[3] = f2bf(v.w);
  }
  __syncthreads();
  int w = t >> 6, l = t & 63, lm = l & 15, lg = l >> 4;
  f32x4 acc[8];
#pragma unroll
  for (int i = 0; i < 8; ++i) acc[i] = (f32x4){0.f, 0.f, 0.f, 0.f};
#pragma unroll
  for (int kk = 0; kk < 4; ++kk) {
    s16x8 a = *(const s16x8*)&qL[w * 16 + lm][kk * 32 + lg * 8];
#pragma unroll
    for (int ct = 0; ct < 8; ++ct) {
      s16x8 bf = *(const s16x8*)(qwb + (ct * 16 + lm) * 128 + kk * 32 + lg * 8);
      acc[ct] = __builtin_amdgcn_mfma_f32_16x16x32_bf16(a, bf, acc[ct], 0, 0, 0);
    }
  }
  const float SC = 0.17677669529663687f;   // 32^-0.5
#pragma unroll
  for (int ct = 0; ct < 8; ++ct) {
    int col = ct * 16 + lm;
    float bb = qb[col];
#pragma unroll
    for (int r = 0; r < 4; ++r) {
      int row = q0 + w * 16 + lg * 4 + r;
      qh[(b * 256 + row) * 128 + col] = f2bf((acc[ct][r] + bb) * SC);
    }
  }
}

// ---------------- kv projection: k row-major bf16, v transposed bf16 ----------------
__global__ __launch_bounds__(256) void kkv(const float* __restrict__ kv,
    const unsigned short* __restrict__ kvwb, const float* __restrict__ kvb,
    unsigned short* __restrict__ kws, unsigned short* __restrict__ vT) {
  __shared__ unsigned short kvL[64][136];
  int b = blockIdx.x >> 1, r0 = (blockIdx.x & 1) << 6;
  int t = threadIdx.x;
  const float4* src = (const float4*)(kv + (b * 128 + r0) * 128);
#pragma unroll
  for (int i = 0; i < 8; ++i) {
    int idx = t + i * 256;
    float4 v = src[idx];
    unsigned short* d = &kvL[idx >> 5][(idx & 31) * 4];
    d[0] = f2bf(v.x); d[1] = f2bf(v.y); d[2] = f2bf(v.z); d[3] = f2bf(v.w);
  }
  __syncthreads();
  int w = t >> 6, l = t & 63, lm = l & 15, lg = l >> 4;
  f32x4 acc[16];
#pragma unroll
  for (int i = 0; i < 16; ++i) acc[i] = (f32x4){0.f, 0.f, 0.f, 0.f};
#pragma unroll
  for (int kk = 0; kk < 4; ++kk) {
    s16x8 a = *(const s16x8*)&kvL[w * 16 + lm][kk * 32 + lg * 8];
#pragma unroll
    for (int ct = 0; ct < 16; ++ct) {
      s16x8 bf = *(const s16x8*)(kvwb + (ct * 16 + lm) * 128 + kk * 32 + lg * 8);
      acc[ct] = __builtin_amdgcn_mfma_f32_16x16x32_bf16(a, bf, acc[ct], 0, 0, 0);
    }
  }
#pragma unroll
  for (int ct = 0; ct < 16; ++ct) {
    int col = ct * 16 + lm;
    float bb = kvb[col];
    if (col < 128) {            // k part: [b][n2][col]
#pragma unroll
      for (int r = 0; r < 4; ++r) {
        int n2 = r0 + w * 16 + lg * 4 + r;
        kws[(b * 128 + n2) * 128 + col] = f2bf(acc[ct][r] + bb);
      }
    } else {                    // v part: transposed vT[b][d][n2]
      int d = col - 128;
      int n2b = r0 + w * 16 + lg * 4;
      s16x4 pack;
#pragma unroll
      for (int r = 0; r < 4; ++r) pack[r] = f2bf(acc[ct][r] + bb);
      *(s16x4*)(vT + (b * 128 + d) * 128 + n2b) = pack;
    }
  }
}

// ---------------- fused attention per (b, h) ----------------
__global__ __launch_bounds__(256) void katt(const unsigned short* __restrict__ qh,
    const unsigned short* __restrict__ kws, const unsigned short* __restrict__ vT,
    const float* __restrict__ bias, const float* __restrict__ mask,
    float* __restrict__ attn_out, unsigned short* __restrict__ xp) {
  __shared__ unsigned short kL[128][40];    // k_h [n2][dh], pad->2-way
  __shared__ unsigned short vTL[32][136];   // vT_h [dh][n2]
  __shared__ unsigned short pL[4][32][136]; // per-wave P bf16
  int b = blockIdx.x >> 2, h = blockIdx.x & 3;
  int t = threadIdx.x;
  {
    const unsigned short* src = kws + (size_t)b * 16384 + h * 32;
#pragma unroll
    for (int i = 0; i < 2; ++i) {
      int idx = t + i * 256;                 // 512 segs: 128 rows x 4 segs of 8
      int row = idx >> 2, seg = idx & 3;
      *(s16x8*)&kL[row][seg * 8] = *(const s16x8*)(src + row * 128 + seg * 8);
    }
    const unsigned short* vsrc = vT + (size_t)b * 16384 + h * 32 * 128;
#pragma unroll
    for (int i = 0; i < 2; ++i) {
      int idx = t + i * 256;                 // 512 segs: 32 rows x 16 segs of 8
      int row = idx >> 4, seg = idx & 15;
      *(s16x8*)&vTL[row][seg * 8] = *(const s16x8*)(vsrc + row * 128 + seg * 8);
    }
  }
  __syncthreads();
  int w = t >> 6, l = t & 63, lm = l & 15, lg = l >> 4;
  const float* biash = bias + h * 32768;
  const float* maskw = mask + (b & 63) * 32768;
  float* attnb = attn_out + ((size_t)(b * 4 + h)) * 32768;
  const f32x4 zero = {0.f, 0.f, 0.f, 0.f};

  for (int p = 0; p < 2; ++p) {
    int qbase = (w * 2 + p) * 32;
    // ---- S = qh_h @ k_h^T (K=32: single MFMA per tile) ----
    s16x8 aq[2];
#pragma unroll
    for (int rt = 0; rt < 2; ++rt)
      aq[rt] = *(const s16x8*)(qh + ((size_t)b * 256 + qbase + rt * 16 + lm) * 128 + h * 32 + lg * 8);
    f32x4 S[2][8];
#pragma unroll
    for (int ct = 0; ct < 8; ++ct) {
      s16x8 bk = *(const s16x8*)&kL[ct * 16 + lm][lg * 8];
#pragma unroll
      for (int rt = 0; rt < 2; ++rt)
        S[rt][ct] = __builtin_amdgcn_mfma_f32_16x16x32_bf16(aq[rt], bk, zero, 0, 0, 0);
    }
    // ---- bias + mask + softmax (rows live in 16-lane groups) ----
#pragma unroll
    for (int rt = 0; rt < 2; ++rt) {
#pragma unroll
      for (int r = 0; r < 4; ++r) {
        int qr = qbase + rt * 16 + lg * 4 + r;
        float v[8];
        float m = -1e30f;
#pragma unroll
        for (int ct = 0; ct < 8; ++ct) {
          int col = ct * 16 + lm;
          float x = S[rt][ct][r] + biash[qr * 128 + col] + maskw[qr * 128 + col];
          v[ct] = x;
          m = fmaxf(m, x);
        }
#pragma unroll
        for (int d = 1; d < 16; d <<= 1) m = fmaxf(m, __shfl_xor(m, d));
        float s = 0.f;
#pragma unroll
        for (int ct = 0; ct < 8; ++ct) { v[ct] = __expf(v[ct] - m); s += v[ct]; }
#pragma unroll
        for (int d = 1; d < 16; d <<= 1) s += __shfl_xor(s, d);
        float inv = 1.0f / s;
        int prow = rt * 16 + lg * 4 + r;
#pragma unroll
        for (int ct = 0; ct < 8; ++ct) {
          float pv = v[ct] * inv;
          int col = ct * 16 + lm;
          attnb[qr * 128 + col] = pv;       // exact fp32 attn output
          pL[w][prow][col] = f2bf(pv);
        }
      }
    }
    // ---- O = P @ v via vT (per-wave LDS, no block barrier needed) ----
    f32x4 O[2][2];
#pragma unroll
    for (int rt = 0; rt < 2; ++rt)
#pragma unroll
      for (int cd = 0; cd < 2; ++cd) O[rt][cd] = zero;
#pragma unroll
    for (int kk = 0; kk < 4; ++kk) {
      s16x8 ap[2];
#pragma unroll
      for (int rt = 0; rt < 2; ++rt)
        ap[rt] = *(const s16x8*)&pL[w][rt * 16 + lm][kk * 32 + lg * 8];
#pragma unroll
      for (int cd = 0; cd < 2; ++cd) {
        s16x8 bv = *(const s16x8*)&vTL[cd * 16 + lm][kk * 32 + lg * 8];
#pragma unroll
        for (int rt = 0; rt < 2; ++rt)
          O[rt][cd] = __builtin_amdgcn_mfma_f32_16x16x32_bf16(ap[rt], bv, O[rt][cd], 0, 0, 0);
      }
    }
#pragma unroll
    for (int rt = 0; rt < 2; ++rt)
#pragma unroll
      for (int cd = 0; cd < 2; ++cd)
#pragma unroll
        for (int r = 0; r < 4; ++r) {
          int qr = qbase + rt * 16 + lg * 4 + r;
          int col = h * 32 + cd * 16 + lm;
          xp[((size_t)b * 256 + qr) * 128 + col] = f2bf(O[rt][cd][r]);
        }
  }
}

// ---------------- output projection: x = xp @ pw^T + pb (f32 out) ----------------
__global__ __launch_bounds__(256) void kp(const unsigned short* __restrict__ xp,
    const unsigned short* __restrict__ pwb, const float* __restrict__ pb,
    float* __restrict__ xout) {
  __shared__ unsigned short xL[64][136];
  int b = blockIdx.x >> 2, r0 = (blockIdx.x & 3) << 6;
  int t = threadIdx.x;
  const unsigned short* src = xp + ((size_t)b * 256 + r0) * 128;
#pragma unroll
  for (int i = 0; i < 4; ++i) {
    int idx = t + i * 256;                   // 1024 segs: 64 rows x 16 segs of 8
    int row = idx >> 4, seg = idx & 15;
    *(s16x8*)&xL[row][seg * 8] = *(const s16x8*)(src + row * 128 + seg * 8);
  }
  __syncthreads();
  int w = t >> 6, l = t & 63, lm = l & 15, lg = l >> 4;
  f32x4 acc[8];
#pragma unroll
  for (int i = 0; i < 8; ++i) acc[i] = (f32x4){0.f, 0.f, 0.f, 0.f};
#pragma unroll
  for (int kk = 0; kk < 4; ++kk) {
    s16x8 a = *(const s16x8*)&xL[w * 16 + lm][kk * 32 + lg * 8];
#pragma unroll
    for (int ct = 0; ct < 8; ++ct) {
      s16x8 bf = *(const s16x8*)(pwb + (ct * 16 + lm) * 128 + kk * 32 + lg * 8);
      acc[ct] = __builtin_amdgcn_mfma_f32_16x16x32_bf16(a, bf, acc[ct], 0, 0, 0);
    }
  }
#pragma unroll
  for (int ct = 0; ct < 8; ++ct) {
    int col = ct * 16 + lm;
    float bb = pb[col];
#pragma unroll
    for (int r = 0; r < 4; ++r) {
      int row = r0 + w * 16 + lg * 4 + r;
      xout[((size_t)b * 256 + row) * 128 + col] = acc[ct][r] + bb;
    }
  }
}

extern "C" void kernel_launch(void* const* d_in, const int* in_sizes, int n_in,
                              void* d_out, int out_size, void* d_ws, size_t ws_size,
                              hipStream_t stream) {
  const float* q    = (const float*)d_in[0];
  const float* kv   = (const float*)d_in[1];
  const float* mask = (const float*)d_in[2];
  const float* qw   = (const float*)d_in[3];
  const float* qb   = (const float*)d_in[4];
  const float* kvw  = (const float*)d_in[5];
  const float* kvb  = (const float*)d_in[6];
  const float* pw   = (const float*)d_in[7];
  const float* pb   = (const float*)d_in[8];
  const float* rpb  = (const float*)d_in[9];
  const int* relidx = (const int*)d_in[10];

  float* xout = (float*)d_out;
  float* attn = xout + (size_t)1024 * 256 * 128;   // 33,554,432

  char* ws = (char*)d_ws;
  unsigned short* qwb  = (unsigned short*)ws;                 // 32 KB
  unsigned short* kvwb = (unsigned short*)(ws + 32768);       // 64 KB
  unsigned short* pwb  = (unsigned short*)(ws + 98304);       // 32 KB
  float*          bias = (float*)(ws + 131072);               // 512 KB
  unsigned short* qh   = (unsigned short*)(ws + 655360);      // 64 MB
  unsigned short* kws  = qh  + (size_t)33554432;              // 32 MB
  unsigned short* vT   = kws + (size_t)16777216;              // 32 MB
  unsigned short* xp   = vT  + (size_t)16777216;              // 64 MB

  kw_prep<<<128, 256, 0, stream>>>(qw, kvw, pw, rpb, relidx, qwb, kvwb, pwb, bias);
  kq<<<4096, 256, 0, stream>>>(q, qwb, qb, qh);
  kkv<<<2048, 256, 0, stream>>>(kv, kvwb, kvb, kws, vT);
  katt<<<4096, 256, 0, stream>>>(qh, kws, vT, bias, mask, attn, xp);
  kp<<<4096, 256, 0, stream>>>(xp, pwb, pb, xout);
}